// Round 1
// baseline (178.292 us; speedup 1.0000x reference)
//
#include <hip/hip_runtime.h>

#define WIN 3
#define KER 7
#define TILE 16
#define HALO 6
#define TDIM (TILE + HALO)   // 22
#define CHUNK 40
#define NCHUNK 4             // 160 / CHUNK
#define DIM 160
#define NBATCH 2

// N = 2 * 160^3
#define NTOT 8192000.0f

__global__ __launch_bounds__(256) void lncc_fused_kernel(
    const float* __restrict__ I,
    const float* __restrict__ J,
    float* __restrict__ out)
{
    __shared__ float sI[TDIM][TDIM];
    __shared__ float sJ[TDIM][TDIM];
    __shared__ float rs[5][TDIM][TILE];
    __shared__ float wsum[4];

    const int tid = threadIdx.x;
    const int tx = tid & 15;
    const int ty = tid >> 4;

    const int tw0 = blockIdx.x * TILE;
    const int th0 = blockIdx.y * TILE;
    const int bz  = blockIdx.z;          // 0 .. NBATCH*NCHUNK-1
    const int b     = bz >> 2;           // batch index (NCHUNK==4)
    const int chunk = bz & 3;
    const int z0  = chunk * CHUNK;

    const size_t plane = (size_t)DIM * DIM;
    const float* Ib = I + (size_t)b * DIM * plane;
    const float* Jb = J + (size_t)b * DIM * plane;

    // ring buffer: 7 z-slices of 2D-boxed sums for the 5 fields (registers,
    // statically indexed via full unroll of the shift)
    float rI[KER], rJ[KER], rI2[KER], rJ2[KER], rIJ[KER];
#pragma unroll
    for (int k = 0; k < KER; ++k) { rI[k]=0.f; rJ[k]=0.f; rI2[k]=0.f; rJ2[k]=0.f; rIJ[k]=0.f; }

    float acc = 0.0f;

    for (int zin = z0 - WIN; zin < z0 + CHUNK + WIN; ++zin) {
        // shift ring (static indices)
#pragma unroll
        for (int k = 0; k < KER - 1; ++k) {
            rI[k]=rI[k+1]; rJ[k]=rJ[k+1]; rI2[k]=rI2[k+1]; rJ2[k]=rJ2[k+1]; rIJ[k]=rIJ[k+1];
        }

        if (zin >= 0 && zin < DIM) {   // block-uniform branch: barriers OK inside
            const float* Ip = Ib + (size_t)zin * plane;
            const float* Jp = Jb + (size_t)zin * plane;

            // ---- load (TDIM x TDIM) tile with halo, zero-padded ----
            for (int idx = tid; idx < TDIM * TDIM; idx += 256) {
                int r = idx / TDIM;
                int c = idx - r * TDIM;
                int gh = th0 + r - WIN;
                int gw = tw0 + c - WIN;
                float vi = 0.f, vj = 0.f;
                if ((unsigned)gh < (unsigned)DIM && (unsigned)gw < (unsigned)DIM) {
                    size_t off = (size_t)gh * DIM + gw;
                    vi = Ip[off];
                    vj = Jp[off];
                }
                sI[r][c] = vi;
                sJ[r][c] = vj;
            }
            __syncthreads();

            // ---- row filter along W for the 5 fields ----
            for (int idx = tid; idx < TDIM * TILE; idx += 256) {
                int r = idx >> 4;          // TILE == 16
                int c = idx & 15;
                float aI=0.f, aJ=0.f, aI2=0.f, aJ2=0.f, aIJ=0.f;
#pragma unroll
                for (int dc = 0; dc < KER; ++dc) {
                    float a = sI[r][c + dc];
                    float bb = sJ[r][c + dc];
                    aI  += a;
                    aJ  += bb;
                    aI2 = fmaf(a,  a,  aI2);
                    aJ2 = fmaf(bb, bb, aJ2);
                    aIJ = fmaf(a,  bb, aIJ);
                }
                rs[0][r][c] = aI;
                rs[1][r][c] = aJ;
                rs[2][r][c] = aI2;
                rs[3][r][c] = aJ2;
                rs[4][r][c] = aIJ;
            }
            __syncthreads();

            // ---- column filter along H -> this thread's (h,w) 2D box sum ----
            float cI=0.f, cJ=0.f, cI2=0.f, cJ2=0.f, cIJ=0.f;
#pragma unroll
            for (int dr = 0; dr < KER; ++dr) {
                cI  += rs[0][ty + dr][tx];
                cJ  += rs[1][ty + dr][tx];
                cI2 += rs[2][ty + dr][tx];
                cJ2 += rs[3][ty + dr][tx];
                cIJ += rs[4][ty + dr][tx];
            }
            rI[KER-1]  = cI;
            rJ[KER-1]  = cJ;
            rI2[KER-1] = cI2;
            rJ2[KER-1] = cJ2;
            rIJ[KER-1] = cIJ;
            __syncthreads();   // protect sI/sJ/rs before next iteration overwrites
        } else {
            rI[KER-1]=0.f; rJ[KER-1]=0.f; rI2[KER-1]=0.f; rJ2[KER-1]=0.f; rIJ[KER-1]=0.f;
        }

        // ---- emit output for zg = zin - WIN (window = slices zin-6 .. zin) ----
        int zg = zin - WIN;
        if (zg >= z0 && zg < z0 + CHUNK) {
            float SI=0.f, SJ=0.f, SI2=0.f, SJ2=0.f, SIJ=0.f;
#pragma unroll
            for (int k = 0; k < KER; ++k) {
                SI += rI[k]; SJ += rJ[k]; SI2 += rI2[k]; SJ2 += rJ2[k]; SIJ += rIJ[k];
            }
            const float inv = 1.0f / 343.0f;   // 7^3
            float mI  = SI  * inv;
            float mJ  = SJ  * inv;
            float mI2 = SI2 * inv;
            float mJ2 = SJ2 * inv;
            float mIJ = SIJ * inv;
            float cross = mIJ - mI * mJ;
            float vI = mI2 - mI * mI;
            float vJ = mJ2 - mJ * mJ;
            float l  = cross * cross / (vI * vJ + 1e-6f);
            acc += l;
        }
    }

    // ---- reduce: wave shuffle, then cross-wave via LDS, one atomic per block ----
#pragma unroll
    for (int off = 32; off > 0; off >>= 1)
        acc += __shfl_down(acc, off, 64);
    if ((tid & 63) == 0) wsum[tid >> 6] = acc;
    __syncthreads();
    if (tid == 0) {
        float t = wsum[0] + wsum[1] + wsum[2] + wsum[3];
        atomicAdd(out, t * (-1.0f / NTOT));
    }
}

extern "C" void kernel_launch(void* const* d_in, const int* in_sizes, int n_in,
                              void* d_out, int out_size, void* d_ws, size_t ws_size,
                              hipStream_t stream) {
    const float* I = (const float*)d_in[0];
    const float* J = (const float*)d_in[1];
    float* out = (float*)d_out;

    // d_out is poisoned with 0xAA before every call — zero it (capture-safe)
    hipMemsetAsync(out, 0, sizeof(float), stream);

    dim3 grid(DIM / TILE, DIM / TILE, NBATCH * NCHUNK);  // 10 x 10 x 8 = 800 blocks
    dim3 block(256);
    lncc_fused_kernel<<<grid, block, 0, stream>>>(I, J, out);
}

// Round 2
// 173.299 us; speedup vs baseline: 1.0288x; 1.0288x over previous
//
#include <hip/hip_runtime.h>

#define WIN 3
#define KER 7
#define TILE 16
#define HALO 6
#define TDIM (TILE + HALO)   // 22
#define SPAD 24              // padded row stride for sI/sJ (banks: 4 row-groups at {0,24,16,8} -> uniform 2-way, free)
#define CHUNK 16
#define NCHUNK 10            // 160 / CHUNK
#define DIM 160
#define NBATCH 2

// N = 2 * 160^3
#define NTOT 8192000.0f

__global__ __launch_bounds__(256) void lncc_fused_kernel(
    const float* __restrict__ I,
    const float* __restrict__ J,
    float* __restrict__ out)
{
    __shared__ float sI[TDIM][SPAD];
    __shared__ float sJ[TDIM][SPAD];
    __shared__ float rs[5][TDIM][TILE];
    __shared__ float wsum[4];

    const int tid = threadIdx.x;
    const int tx = tid & 15;
    const int ty = tid >> 4;

    const int tw0 = blockIdx.x * TILE;
    const int th0 = blockIdx.y * TILE;
    const int bz  = blockIdx.z;          // 0 .. NBATCH*NCHUNK-1
    const int b     = bz / NCHUNK;       // batch index
    const int chunk = bz - b * NCHUNK;
    const int z0  = chunk * CHUNK;

    const size_t plane = (size_t)DIM * DIM;
    const float* Ib = I + (size_t)b * DIM * plane;
    const float* Jb = J + (size_t)b * DIM * plane;

    // ring buffer of per-slice 2D box sums (statically indexed; shifted)
    float rI[KER], rJ[KER], rI2[KER], rJ2[KER], rIJ[KER];
#pragma unroll
    for (int k = 0; k < KER; ++k) { rI[k]=0.f; rJ[k]=0.f; rI2[k]=0.f; rJ2[k]=0.f; rIJ[k]=0.f; }

    // running z-window sums (add new, subtract slice falling out of window)
    float SI=0.f, SJ=0.f, SI2=0.f, SJ2=0.f, SIJ=0.f;

    float acc = 0.0f;

    for (int zin = z0 - WIN; zin < z0 + CHUNK + WIN; ++zin) {
        float cI=0.f, cJ=0.f, cI2=0.f, cJ2=0.f, cIJ=0.f;

        if (zin >= 0 && zin < DIM) {   // block-uniform branch: barriers OK inside
            const float* Ip = Ib + (size_t)zin * plane;
            const float* Jp = Jb + (size_t)zin * plane;

            // ---- load (TDIM x TDIM) tile with halo, zero-padded ----
            for (int idx = tid; idx < TDIM * TDIM; idx += 256) {
                int r = idx / TDIM;
                int c = idx - r * TDIM;
                int gh = th0 + r - WIN;
                int gw = tw0 + c - WIN;
                float vi = 0.f, vj = 0.f;
                if ((unsigned)gh < (unsigned)DIM && (unsigned)gw < (unsigned)DIM) {
                    size_t off = (size_t)gh * DIM + gw;
                    vi = Ip[off];
                    vj = Jp[off];
                }
                sI[r][c] = vi;
                sJ[r][c] = vj;
            }
            __syncthreads();   // B1: loads visible to row filter

            // ---- row filter along W for the 5 fields ----
            for (int idx = tid; idx < TDIM * TILE; idx += 256) {
                int r = idx >> 4;          // TILE == 16
                int c = idx & 15;
                float aI=0.f, aJ=0.f, aI2=0.f, aJ2=0.f, aIJ=0.f;
#pragma unroll
                for (int dc = 0; dc < KER; ++dc) {
                    float a  = sI[r][c + dc];
                    float bb = sJ[r][c + dc];
                    aI  += a;
                    aJ  += bb;
                    aI2 = fmaf(a,  a,  aI2);
                    aJ2 = fmaf(bb, bb, aJ2);
                    aIJ = fmaf(a,  bb, aIJ);
                }
                rs[0][r][c] = aI;
                rs[1][r][c] = aJ;
                rs[2][r][c] = aI2;
                rs[3][r][c] = aJ2;
                rs[4][r][c] = aIJ;
            }
            __syncthreads();   // B2: rs visible to column filter
            // NOTE: no 3rd barrier needed. After B2 this iteration only reads rs;
            // the next iteration's sI/sJ writes precede its B1, and every wave
            // reaches that B1 only after all waves passed this B2 (finished
            // reading rs is enforced by arrival at next B1 before rs rewrite).

            // ---- column filter along H -> this thread's (h,w) 2D box sum ----
#pragma unroll
            for (int dr = 0; dr < KER; ++dr) {
                cI  += rs[0][ty + dr][tx];
                cJ  += rs[1][ty + dr][tx];
                cI2 += rs[2][ty + dr][tx];
                cJ2 += rs[3][ty + dr][tx];
                cIJ += rs[4][ty + dr][tx];
            }
        }

        // ---- update running window: add new slice, drop oldest ----
        SI  += cI  - rI[0];
        SJ  += cJ  - rJ[0];
        SI2 += cI2 - rI2[0];
        SJ2 += cJ2 - rJ2[0];
        SIJ += cIJ - rIJ[0];
#pragma unroll
        for (int k = 0; k < KER - 1; ++k) {
            rI[k]=rI[k+1]; rJ[k]=rJ[k+1]; rI2[k]=rI2[k+1]; rJ2[k]=rJ2[k+1]; rIJ[k]=rIJ[k+1];
        }
        rI[KER-1]=cI; rJ[KER-1]=cJ; rI2[KER-1]=cI2; rJ2[KER-1]=cJ2; rIJ[KER-1]=cIJ;

        // ---- emit output for zg = zin - WIN (window = slices zin-6 .. zin) ----
        int zg = zin - WIN;
        if (zg >= z0) {   // zg < z0+CHUNK always true (loop bound)
            const float inv = 1.0f / 343.0f;   // 7^3
            float mI  = SI  * inv;
            float mJ  = SJ  * inv;
            float mI2 = SI2 * inv;
            float mJ2 = SJ2 * inv;
            float mIJ = SIJ * inv;
            float cross = mIJ - mI * mJ;
            float vI = mI2 - mI * mI;
            float vJ = mJ2 - mJ * mJ;
            float l  = cross * cross / (vI * vJ + 1e-6f);
            acc += l;
        }
    }

    // ---- reduce: wave shuffle, then cross-wave via LDS, one atomic per block ----
#pragma unroll
    for (int off = 32; off > 0; off >>= 1)
        acc += __shfl_down(acc, off, 64);
    if ((tid & 63) == 0) wsum[tid >> 6] = acc;
    __syncthreads();
    if (tid == 0) {
        float t = wsum[0] + wsum[1] + wsum[2] + wsum[3];
        atomicAdd(out, t * (-1.0f / NTOT));
    }
}

extern "C" void kernel_launch(void* const* d_in, const int* in_sizes, int n_in,
                              void* d_out, int out_size, void* d_ws, size_t ws_size,
                              hipStream_t stream) {
    const float* I = (const float*)d_in[0];
    const float* J = (const float*)d_in[1];
    float* out = (float*)d_out;

    // d_out is poisoned with 0xAA before every call — zero it (capture-safe)
    hipMemsetAsync(out, 0, sizeof(float), stream);

    dim3 grid(DIM / TILE, DIM / TILE, NBATCH * NCHUNK);  // 10 x 10 x 20 = 2000 blocks
    dim3 block(256);
    lncc_fused_kernel<<<grid, block, 0, stream>>>(I, J, out);
}

// Round 3
// 153.459 us; speedup vs baseline: 1.1618x; 1.1293x over previous
//
#include <hip/hip_runtime.h>

#define DIM 160
#define TW 32
#define TH 16
#define RROWS (TH + 6)        // 22
#define CHUNK 16
#define NCHUNK (DIM / CHUNK)  // 10
#define NBATCH 2
#define NTOT 8192000.0f       // 2 * 160^3

__global__ __launch_bounds__(256) void lncc_fused_kernel(
    const float* __restrict__ I,
    const float* __restrict__ J,
    float* __restrict__ out)
{
    // double-buffered row-sum planes: [buf][field][row][col], 28,160 B
    __shared__ __align__(16) float rs[2][5][RROWS][TW];
    __shared__ float wsum[4];

    const int tid = threadIdx.x;
    // col-stage coords: thread -> (h=ty, w=2*tx, 2*tx+1)
    const int tx = tid & 15;
    const int ty = tid >> 4;
    // row-stage coords: thread -> (row rr, 4-wide group rg)
    const int rr = tid >> 3;          // 0..31
    const int rg = tid & 7;           // 0..7
    const bool rowActive = (rr < RROWS);

    const int tw0 = blockIdx.x * TW;
    const int th0 = blockIdx.y * TH;
    const int bz  = blockIdx.z;
    const int b     = bz / NCHUNK;
    const int chunk = bz - b * NCHUNK;
    const int z0  = chunk * CHUNK;

    const size_t plane = (size_t)DIM * DIM;
    const float* Ib = I + (size_t)b * DIM * plane;
    const float* Jb = J + (size_t)b * DIM * plane;

    const int gh = th0 + rr - 3;
    const bool rowValid = rowActive && ((unsigned)gh < (unsigned)DIM);
    const int gw0 = tw0 + 4 * rg - 4;                    // start col of first float4
    const bool ok0 = (unsigned)gw0       <= (unsigned)(DIM - 4);
    const bool ok1 = (unsigned)(gw0 + 4) <= (unsigned)(DIM - 4);
    const bool ok2 = (unsigned)(gw0 + 8) <= (unsigned)(DIM - 4);
    const size_t rowbase = (size_t)gh * DIM + gw0;       // used only when rowValid

    // z-ring of 2D box sums: [field][j][slot]; statically indexed (full unroll)
    float rng[5][2][7];
#pragma unroll
    for (int f = 0; f < 5; ++f)
#pragma unroll
        for (int j = 0; j < 2; ++j)
#pragma unroll
            for (int k = 0; k < 7; ++k) rng[f][j][k] = 0.f;

    float S[5][2];
#pragma unroll
    for (int f = 0; f < 5; ++f) { S[f][0] = 0.f; S[f][1] = 0.f; }

    float acc = 0.f;
    int p = 0;

    for (int zin = z0 - 3; zin < z0 + CHUNK + 3; ++zin) {
        const bool zv = (zin >= 0) && (zin < DIM);   // block-uniform
        float Cx[5], Cy[5];
#pragma unroll
        for (int f = 0; f < 5; ++f) { Cx[f] = 0.f; Cy[f] = 0.f; }

        if (zv) {
            // ---------- row stage: global float4 -> sliding W-sums -> rs ----------
            if (rowActive) {
                float4 a0 = {0,0,0,0}, a1 = {0,0,0,0}, a2 = {0,0,0,0};
                float4 b0 = {0,0,0,0}, b1 = {0,0,0,0}, b2 = {0,0,0,0};
                if (rowValid) {
                    const float* Ip = Ib + (size_t)zin * plane + rowbase;
                    const float* Jp = Jb + (size_t)zin * plane + rowbase;
                    if (ok0) { a0 = *(const float4*)(Ip);     b0 = *(const float4*)(Jp);     }
                    if (ok1) { a1 = *(const float4*)(Ip + 4); b1 = *(const float4*)(Jp + 4); }
                    if (ok2) { a2 = *(const float4*)(Ip + 8); b2 = *(const float4*)(Jp + 8); }
                }
                float vI[12] = {a0.x,a0.y,a0.z,a0.w, a1.x,a1.y,a1.z,a1.w, a2.x,a2.y,a2.z,a2.w};
                float vJ[12] = {b0.x,b0.y,b0.z,b0.w, b1.x,b1.y,b1.z,b1.w, b2.x,b2.y,b2.z,b2.w};

                float sI=0.f, sJ=0.f, sI2=0.f, sJ2=0.f, sIJ=0.f;
#pragma unroll
                for (int i = 1; i < 8; ++i) {
                    float a = vI[i], c = vJ[i];
                    sI += a; sJ += c;
                    sI2 = fmaf(a, a, sI2);
                    sJ2 = fmaf(c, c, sJ2);
                    sIJ = fmaf(a, c, sIJ);
                }
                float wI[4], wJ[4], wI2[4], wJ2[4], wIJ[4];
                wI[0]=sI; wJ[0]=sJ; wI2[0]=sI2; wJ2[0]=sJ2; wIJ[0]=sIJ;
#pragma unroll
                for (int k = 1; k < 4; ++k) {
                    float an = vI[7+k], cn = vJ[7+k];
                    float ao = vI[k],   co = vJ[k];
                    sI  += an - ao;
                    sJ  += cn - co;
                    sI2 += fmaf(an, an, -(ao*ao));
                    sJ2 += fmaf(cn, cn, -(co*co));
                    sIJ += fmaf(an, cn, -(ao*co));
                    wI[k]=sI; wJ[k]=sJ; wI2[k]=sI2; wJ2[k]=sJ2; wIJ[k]=sIJ;
                }
                const int cc = 4 * rg;
                *(float4*)&rs[p][0][rr][cc] = make_float4(wI[0],  wI[1],  wI[2],  wI[3]);
                *(float4*)&rs[p][1][rr][cc] = make_float4(wJ[0],  wJ[1],  wJ[2],  wJ[3]);
                *(float4*)&rs[p][2][rr][cc] = make_float4(wI2[0], wI2[1], wI2[2], wI2[3]);
                *(float4*)&rs[p][3][rr][cc] = make_float4(wJ2[0], wJ2[1], wJ2[2], wJ2[3]);
                *(float4*)&rs[p][4][rr][cc] = make_float4(wIJ[0], wIJ[1], wIJ[2], wIJ[3]);
            }
            __syncthreads();   // rs[p] ready; also fences re-write of rs[p] from 2 slices ago

            // ---------- col stage: 7-row sums via float2 reads ----------
#pragma unroll
            for (int dr = 0; dr < 7; ++dr) {
                const int r = ty + dr;
#pragma unroll
                for (int f = 0; f < 5; ++f) {
                    const float2 v = *(const float2*)&rs[p][f][r][2 * tx];
                    Cx[f] += v.x;
                    Cy[f] += v.y;
                }
            }
            p ^= 1;
        }

        // ---------- z running window: add new slice, drop oldest ----------
#pragma unroll
        for (int f = 0; f < 5; ++f) {
            S[f][0] += Cx[f] - rng[f][0][0];
            S[f][1] += Cy[f] - rng[f][1][0];
#pragma unroll
            for (int k = 0; k < 6; ++k) {
                rng[f][0][k] = rng[f][0][k+1];
                rng[f][1][k] = rng[f][1][k+1];
            }
            rng[f][0][6] = Cx[f];
            rng[f][1][6] = Cy[f];
        }

        // ---------- emit for zg = zin - 3 ----------
        if (zin - 3 >= z0) {
            const float inv = 1.0f / 343.0f;   // 7^3
#pragma unroll
            for (int j = 0; j < 2; ++j) {
                float mI  = S[0][j] * inv;
                float mJ  = S[1][j] * inv;
                float mI2 = S[2][j] * inv;
                float mJ2 = S[3][j] * inv;
                float mIJ = S[4][j] * inv;
                float cross = mIJ - mI * mJ;
                float vI_ = mI2 - mI * mI;
                float vJ_ = mJ2 - mJ * mJ;
                acc += cross * cross / (vI_ * vJ_ + 1e-6f);
            }
        }
    }

    // ---------- block reduce -> one atomic ----------
#pragma unroll
    for (int off = 32; off > 0; off >>= 1)
        acc += __shfl_down(acc, off, 64);
    if ((tid & 63) == 0) wsum[tid >> 6] = acc;
    __syncthreads();
    if (tid == 0) {
        float t = wsum[0] + wsum[1] + wsum[2] + wsum[3];
        atomicAdd(out, t * (-1.0f / NTOT));
    }
}

extern "C" void kernel_launch(void* const* d_in, const int* in_sizes, int n_in,
                              void* d_out, int out_size, void* d_ws, size_t ws_size,
                              hipStream_t stream) {
    const float* I = (const float*)d_in[0];
    const float* J = (const float*)d_in[1];
    float* out = (float*)d_out;

    hipMemsetAsync(out, 0, sizeof(float), stream);

    dim3 grid(DIM / TW, DIM / TH, NBATCH * NCHUNK);   // 5 x 10 x 20 = 1000 blocks
    dim3 block(256);
    lncc_fused_kernel<<<grid, block, 0, stream>>>(I, J, out);
}